// Round 1
// baseline (1444.325 us; speedup 1.0000x reference)
//
#include <hip/hip_runtime.h>
#include <stdint.h>

// ---------------------------------------------------------------------------
// SPP (spatial pyramid pooling) on point cloud:
//   out[n] = b + W0@mean_global[batch(n)] + W2@mean2[seg2(n)] + W4@mean4[seg4(n)] + W8@mean8[seg8(n)]
// Strategy:
//   1. atomically scatter feats into k=2 segment sums (finest level only)
//   2. build k=4, k=8, global sums by 8-child tree reduction (no atomics)
//   3. project each level's segment means through its W-chunk -> Y_l[seg][96] (bf16)
//   4. final gather-add per point (pure streaming)
// ---------------------------------------------------------------------------

#define N_PTS   1048576
#define CCH     64
#define OUTS    96
#define NB      4
#define N2SEG   (NB*64*64*64)   // 1,048,576
#define N4SEG   (NB*32*32*32)   // 131,072
#define N8SEG   (NB*16*16*16)   // 16,384

#define OFF_SUMS2  ((size_t)0)            // N2SEG*64 f32    = 268,435,456 B
#define OFF_CNT2   ((size_t)268435456)    // N2SEG u32       =   4,194,304 B
#define OFF_SUMS4  ((size_t)272629760)    // N4SEG*64 f32    =  33,554,432 B
#define OFF_CNT4   ((size_t)306184192)    // N4SEG u32       =     524,288 B
#define OFF_SUMS8  ((size_t)306708480)    // N8SEG*64 f32    =   4,194,304 B
#define OFF_CNT8   ((size_t)310902784)    // N8SEG u32       =      65,536 B
#define OFF_SUMS0  ((size_t)310968320)    // 4*64 f32 (pad)  =       1,024 B
#define OFF_CNT0   ((size_t)310969344)    // 4 u32 (pad)     =         256 B
#define OFF_WT     ((size_t)310969600)    // 256*96 f32      =      98,304 B
#define OFF_Y0     ((size_t)311067904)    // 4*48 u32 (pad)  =       1,024 B
#define OFF_Y8     ((size_t)311068928)    // N8SEG*48 u32    =   3,145,728 B
#define OFF_Y4     ((size_t)314214656)    // N4SEG*48 u32    =  25,165,824 B
#define OFF_Y2     ((size_t)339380480)    // N2SEG*48 u32    = 201,326,592 B
#define WS_NEEDED  ((size_t)540707072)

__device__ __forceinline__ unsigned pack_bf16x2(float a, float b) {
  unsigned ua = __float_as_uint(a);
  unsigned ub = __float_as_uint(b);
  ua = (ua + 0x7fffu + ((ua >> 16) & 1u)) >> 16;   // RNE f32->bf16
  ub = (ub + 0x7fffu + ((ub >> 16) & 1u)) >> 16;
  return (ub << 16) | ua;
}

__device__ __forceinline__ float2 unpack_bf16x2(unsigned u) {
  float2 r;
  r.x = __uint_as_float(u << 16);
  r.y = __uint_as_float(u & 0xffff0000u);
  return r;
}

// WT[col*96 + o] = W[o*256 + col]
__global__ __launch_bounds__(256) void k_wt(const float* __restrict__ W,
                                            float* __restrict__ WT) {
  int tid = blockIdx.x * 256 + threadIdx.x;           // < 24576
  unsigned q5 = ((unsigned)tid) >> 5;
  int col = (int)((q5 * 0xAAAAAAABull) >> 33);        // tid / 96
  int o = tid - col * 96;
  WT[tid] = W[(size_t)o * 256 + col];
}

// scatter feats into finest (k=2) level: 64 lanes = 64 channels of one point
__global__ __launch_bounds__(256) void k_scatter2(
    const float* __restrict__ feats, const int* __restrict__ coords,
    const int* __restrict__ batch, float* __restrict__ sums2,
    unsigned* __restrict__ cnt2)
{
  int lane = threadIdx.x & 63;
  int pg = (blockIdx.x * 256 + threadIdx.x) >> 6;
  int stride = (gridDim.x * 256) >> 6;
  for (int p = pg; p < N_PTS; p += stride) {
    float f = feats[(size_t)p * CCH + lane];
    int b = batch[p];
    int x = coords[3 * p + 0], y = coords[3 * p + 1], z = coords[3 * p + 2];
    int s2 = ((b * 64 + (x >> 1)) * 64 + (y >> 1)) * 64 + (z >> 1);
    unsafeAtomicAdd(&sums2[(size_t)s2 * CCH + lane], f);
    if (lane == 0) atomicAdd(&cnt2[s2], 1u);
  }
}

// coarse[sc] = sum of 8 fine children (fine grid = 2*coarse grid)
__global__ __launch_bounds__(256) void k_down(
    const float* __restrict__ sumsF, const unsigned* __restrict__ cntF,
    float* __restrict__ sumsC, unsigned* __restrict__ cntC, int lgC, int nC)
{
  int tid = blockIdx.x * 256 + threadIdx.x;
  int sc = tid >> 6, c = tid & 63;
  if (sc >= nC) return;
  int CG = 1 << lgC;
  int b = sc >> (3 * lgC);
  int r = sc & ((1 << (3 * lgC)) - 1);
  int x = r >> (2 * lgC), y = (r >> lgC) & (CG - 1), z = r & (CG - 1);
  int FG = CG << 1;
  float s = 0.f;
  unsigned cn = 0;
  #pragma unroll
  for (int dx = 0; dx < 2; ++dx)
    #pragma unroll
    for (int dy = 0; dy < 2; ++dy)
      #pragma unroll
      for (int dz = 0; dz < 2; ++dz) {
        int sf = ((b * FG + 2 * x + dx) * FG + (2 * y + dy)) * FG + (2 * z + dz);
        s += sumsF[(size_t)sf * 64 + c];
        if (c == 0) cn += cntF[sf];
      }
  sumsC[(size_t)sc * 64 + c] = s;
  if (c == 0) cntC[sc] = cn;
}

// global (per-batch) sums from k=8 level; 1 block per batch
__global__ __launch_bounds__(256) void k_global(
    const float* __restrict__ sums8, const unsigned* __restrict__ cnt8,
    float* __restrict__ sums0, unsigned* __restrict__ cnt0)
{
  __shared__ float red[256];
  __shared__ unsigned redc[256];
  int b = blockIdx.x;
  int t = threadIdx.x, c = t & 63, g = t >> 6;
  float s = 0.f;
  for (int cell = g; cell < 4096; cell += 4)
    s += sums8[((size_t)(b * 4096 + cell)) * 64 + c];
  unsigned cn = 0;
  for (int cell = t; cell < 4096; cell += 256)
    cn += cnt8[b * 4096 + cell];
  red[t] = s;
  redc[t] = cn;
  __syncthreads();
  if (g == 0) sums0[b * 64 + c] = red[c] + red[64 + c] + red[128 + c] + red[192 + c];
  if (t == 0) {
    unsigned tot = 0;
    for (int i = 0; i < 256; ++i) tot += redc[i];
    cnt0[b] = tot;
  }
}

// Y[seg][0:96) = (W chunk) @ (sums[seg]/max(cnt,1)), stored bf16-packed (48 u32)
// lane = seg; W rows are wave-uniform loads (scalar path); acc[96] in VGPRs.
__global__ __launch_bounds__(256) void k_project(
    const float* __restrict__ sums, const unsigned* __restrict__ cnt,
    unsigned* __restrict__ Yu, const float* __restrict__ WT, int col0, int nseg)
{
  __shared__ unsigned lds[4][64 * 49];
  int t = threadIdx.x, w = t >> 6, lane = t & 63;
  int seg0 = blockIdx.x * 256 + w * 64;
  int seg = seg0 + lane;
  int segc = seg < nseg ? seg : (nseg - 1);
  float acc[OUTS];
  #pragma unroll
  for (int o = 0; o < OUTS; ++o) acc[o] = 0.f;
  const float4* sp = (const float4*)(sums + (size_t)segc * 64);
  for (int c4 = 0; c4 < 16; ++c4) {
    float4 m = sp[c4];
    const float* wr = WT + (size_t)(col0 + c4 * 4) * OUTS;
    #pragma unroll
    for (int o = 0; o < OUTS; ++o) acc[o] = fmaf(wr[o], m.x, acc[o]);
    #pragma unroll
    for (int o = 0; o < OUTS; ++o) acc[o] = fmaf(wr[OUTS + o], m.y, acc[o]);
    #pragma unroll
    for (int o = 0; o < OUTS; ++o) acc[o] = fmaf(wr[2 * OUTS + o], m.z, acc[o]);
    #pragma unroll
    for (int o = 0; o < OUTS; ++o) acc[o] = fmaf(wr[3 * OUTS + o], m.w, acc[o]);
  }
  unsigned cv = cnt[segc];
  float rc = 1.0f / (float)(cv > 1u ? cv : 1u);
  #pragma unroll
  for (int o2 = 0; o2 < 48; ++o2)
    lds[w][lane * 49 + o2] = pack_bf16x2(acc[2 * o2] * rc, acc[2 * o2 + 1] * rc);
  __syncthreads();
  int covered = nseg - seg0;
  if (covered > 64) covered = 64;
  if (covered < 0) covered = 0;
  unsigned* dst = Yu + (size_t)seg0 * 48;
  for (int k = 0; k < 48; ++k) {
    int g = k * 64 + lane;
    unsigned q = ((unsigned)g) >> 4;
    int sseg = (int)((q * 0xAAAAAAABull) >> 33);   // g / 48
    int o2 = g - sseg * 48;
    if (sseg < covered) dst[g] = lds[w][sseg * 49 + o2];   // coalesced
  }
}

// out[p][2*o2 .. 2*o2+1] = b + Y0 + Y2 + Y4 + Y8   (thread = (p, o2), tid = p*48+o2)
__global__ __launch_bounds__(256) void k_final(
    const int* __restrict__ coords, const int* __restrict__ batch,
    const float* __restrict__ bias,
    const unsigned* __restrict__ Y0, const unsigned* __restrict__ Y2,
    const unsigned* __restrict__ Y4, const unsigned* __restrict__ Y8,
    float* __restrict__ out)
{
  int tid = blockIdx.x * 256 + threadIdx.x;   // < N_PTS*48
  unsigned q4 = ((unsigned)tid) >> 4;
  int p = (int)((q4 * 0xAAAAAAABull) >> 33);  // tid / 48
  int o2 = tid - p * 48;
  int b = batch[p];
  int x = coords[3 * p], y = coords[3 * p + 1], z = coords[3 * p + 2];
  int s2 = ((b * 64 + (x >> 1)) * 64 + (y >> 1)) * 64 + (z >> 1);
  int s4 = ((b * 32 + (x >> 2)) * 32 + (y >> 2)) * 32 + (z >> 2);
  int s8 = ((b * 16 + (x >> 3)) * 16 + (y >> 3)) * 16 + (z >> 3);
  float2 r = ((const float2*)bias)[o2];
  float2 a0 = unpack_bf16x2(Y0[b * 48 + o2]);
  float2 a2 = unpack_bf16x2(Y2[(size_t)s2 * 48 + o2]);
  float2 a4 = unpack_bf16x2(Y4[(size_t)s4 * 48 + o2]);
  float2 a8 = unpack_bf16x2(Y8[(size_t)s8 * 48 + o2]);
  r.x += a0.x + a2.x + a4.x + a8.x;
  r.y += a0.y + a2.y + a4.y + a8.y;
  ((float2*)out)[tid] = r;
}

extern "C" void kernel_launch(void* const* d_in, const int* in_sizes, int n_in,
                              void* d_out, int out_size, void* d_ws, size_t ws_size,
                              hipStream_t stream)
{
  const float* feats  = (const float*)d_in[0];
  const int*   coords = (const int*)d_in[1];
  const int*   batch  = (const int*)d_in[2];
  const float* W      = (const float*)d_in[3];
  const float* bias   = (const float*)d_in[4];
  float* out = (float*)d_out;
  char* ws = (char*)d_ws;
  if (ws_size < WS_NEEDED) return;

  float*    sums2 = (float*)(ws + OFF_SUMS2);
  unsigned* cnt2  = (unsigned*)(ws + OFF_CNT2);
  float*    sums4 = (float*)(ws + OFF_SUMS4);
  unsigned* cnt4  = (unsigned*)(ws + OFF_CNT4);
  float*    sums8 = (float*)(ws + OFF_SUMS8);
  unsigned* cnt8  = (unsigned*)(ws + OFF_CNT8);
  float*    sums0 = (float*)(ws + OFF_SUMS0);
  unsigned* cnt0  = (unsigned*)(ws + OFF_CNT0);
  float*    WT    = (float*)(ws + OFF_WT);
  unsigned* Y0    = (unsigned*)(ws + OFF_Y0);
  unsigned* Y8    = (unsigned*)(ws + OFF_Y8);
  unsigned* Y4    = (unsigned*)(ws + OFF_Y4);
  unsigned* Y2    = (unsigned*)(ws + OFF_Y2);

  // zero the atomic-accumulated regions (sums2 + cnt2 are contiguous at front)
  hipMemsetAsync(ws, 0, OFF_SUMS4, stream);

  k_wt<<<96, 256, 0, stream>>>(W, WT);
  k_scatter2<<<8192, 256, 0, stream>>>(feats, coords, batch, sums2, cnt2);
  k_down<<<(N4SEG * 64) / 256, 256, 0, stream>>>(sums2, cnt2, sums4, cnt4, 5, N4SEG);
  k_down<<<(N8SEG * 64) / 256, 256, 0, stream>>>(sums4, cnt4, sums8, cnt8, 4, N8SEG);
  k_global<<<NB, 256, 0, stream>>>(sums8, cnt8, sums0, cnt0);
  k_project<<<(N2SEG + 255) / 256, 256, 0, stream>>>(sums2, cnt2, Y2, WT, 64, N2SEG);
  k_project<<<(N4SEG + 255) / 256, 256, 0, stream>>>(sums4, cnt4, Y4, WT, 128, N4SEG);
  k_project<<<(N8SEG + 255) / 256, 256, 0, stream>>>(sums8, cnt8, Y8, WT, 192, N8SEG);
  k_project<<<1, 256, 0, stream>>>(sums0, cnt0, Y0, WT, 0, NB);
  k_final<<<(N_PTS * 48) / 256, 256, 0, stream>>>(coords, batch, bias, Y0, Y2, Y4, Y8, out);
}

// Round 2
// 608.793 us; speedup vs baseline: 2.3724x; 2.3724x over previous
//
#include <hip/hip_runtime.h>
#include <stdint.h>

// ---------------------------------------------------------------------------
// SPP: out[n] = b + W @ [mean0(b) | mean2(s2) | mean4(s4) | mean8(s8)]
// v2: bf16 pk-atomic scatter -> bf16 sum pyramid -> single fused MFMA
//     gather-GEMM (M=1M, N=96, K=256) with per-level acc + epilogue 1/cnt.
// ---------------------------------------------------------------------------

#define N_PTS   1048576
#define NB      4
#define N2SEG   (NB*64*64*64)   // 1,048,576
#define N4SEG   (NB*32*32*32)   // 131,072
#define N8SEG   (NB*16*16*16)   // 16,384

typedef unsigned int uint;

// workspace offsets (bytes)
#define OFF_SUMS2  ((size_t)0)            // N2SEG*64 bf16 = 134,217,728
#define OFF_CNT2   ((size_t)134217728)    // N2SEG u32     =   4,194,304
#define OFF_SUMS4  ((size_t)138412032)    // N4SEG*64 bf16 =  16,777,216
#define OFF_CNT4   ((size_t)155189248)    // N4SEG u32     =     524,288
#define OFF_SUMS8  ((size_t)155713536)    // N8SEG*64 bf16 =   2,097,152
#define OFF_CNT8   ((size_t)157810688)    // N8SEG u32     =      65,536
#define OFF_SUMS0  ((size_t)157876224)    // 4*64 bf16 (pad 1024)
#define OFF_CNT0   ((size_t)157877248)    // 4 u32 (pad 256)
#define OFF_WF     ((size_t)157877504)    // 48 KB frag-ready W
#define WS_NEEDED  ((size_t)157926656)

typedef short s8v __attribute__((ext_vector_type(8)));   // 8 bf16 (4 VGPR)
typedef float f4v __attribute__((ext_vector_type(4)));   // MFMA C/D

__device__ __forceinline__ uint pack_bf16x2(float a, float b) {
  uint ua = __float_as_uint(a), ub = __float_as_uint(b);
  ua = (ua + 0x7fffu + ((ua >> 16) & 1u)) >> 16;   // RNE
  ub = (ub + 0x7fffu + ((ub >> 16) & 1u)) >> 16;
  return (ub << 16) | ua;
}
__device__ __forceinline__ float bflo(uint u) { return __uint_as_float(u << 16); }
__device__ __forceinline__ float bfhi(uint u) { return __uint_as_float(u & 0xffff0000u); }

// ---- frag-ready W: Wf[((kt*6+nt)*64+l)*4+d] = pack(W[n][k], W[n][k+1])
//      n = nt*16+(l&15), k = kt*32+(l>>4)*8+2d   (B[k][n] = W[n][k])
__global__ __launch_bounds__(256) void k_wf(const float* __restrict__ W,
                                            uint* __restrict__ Wf) {
  int idx = blockIdx.x * 256 + threadIdx.x;        // < 12288
  int d = idx & 3, l = (idx >> 2) & 63, ktnt = idx >> 8;
  int kt = ktnt / 6, nt = ktnt - kt * 6;
  int n = nt * 16 + (l & 15);
  int k = kt * 32 + (l >> 4) * 8 + d * 2;
  Wf[idx] = pack_bf16x2(W[n * 256 + k], W[n * 256 + k + 1]);
}

// ---- scatter: 2 points per wave, lane = (half, channel-pair), pk-bf16 atomics
__global__ __launch_bounds__(256) void k_scatter2(
    const float* __restrict__ feats, const int* __restrict__ coords,
    const int* __restrict__ batch, uint* __restrict__ sums2,
    uint* __restrict__ cnt2)
{
  int l = threadIdx.x & 63;
  int c2 = l & 31, half = l >> 5;
  int wid = (blockIdx.x * 256 + threadIdx.x) >> 6;
  int nw = (gridDim.x * 256) >> 6;
  for (int p0 = wid * 2; p0 < N_PTS; p0 += nw * 2) {
    int p = p0 + half;
    float2 f = ((const float2*)feats)[(size_t)p * 32 + c2];
    int b = batch[p];
    int x = coords[3 * p], y = coords[3 * p + 1], z = coords[3 * p + 2];
    int s2 = ((b * 64 + (x >> 1)) * 64 + (y >> 1)) * 64 + (z >> 1);
    uint pk = pack_bf16x2(f.x, f.y);
    uint64_t addr = (uint64_t)(uintptr_t)(sums2 + (size_t)s2 * 32 + c2);
    asm volatile("global_atomic_pk_add_bf16 %0, %1, off"
                 :: "v"(addr), "v"(pk) : "memory");
    if (c2 == 0) atomicAdd(&cnt2[s2], 1u);
  }
}

// ---- 8-child tree reduction, bf16 dword granularity (thread = (sc, c2))
__global__ __launch_bounds__(256) void k_down_bf(
    const uint* __restrict__ sumsF, const uint* __restrict__ cntF,
    uint* __restrict__ sumsC, uint* __restrict__ cntC, int lgC, int nC)
{
  int tid = blockIdx.x * 256 + threadIdx.x;
  int sc = tid >> 5, c2 = tid & 31;
  if (sc >= nC) return;
  int CG = 1 << lgC, FG = CG << 1;
  int b = sc >> (3 * lgC);
  int r = sc & ((1 << (3 * lgC)) - 1);
  int x = r >> (2 * lgC), y = (r >> lgC) & (CG - 1), z = r & (CG - 1);
  float sx = 0.f, sy = 0.f;
  uint cn = 0;
  #pragma unroll
  for (int dx = 0; dx < 2; ++dx)
    #pragma unroll
    for (int dy = 0; dy < 2; ++dy)
      #pragma unroll
      for (int dz = 0; dz < 2; ++dz) {
        int sf = ((b * FG + 2 * x + dx) * FG + (2 * y + dy)) * FG + (2 * z + dz);
        uint u = sumsF[(size_t)sf * 32 + c2];
        sx += bflo(u); sy += bfhi(u);
        if (c2 == 0) cn += cntF[sf];
      }
  sumsC[(size_t)sc * 32 + c2] = pack_bf16x2(sx, sy);
  if (c2 == 0) cntC[sc] = cn;
}

// ---- per-batch global sums from k=8 level
__global__ __launch_bounds__(256) void k_global_bf(
    const uint* __restrict__ sums8, const uint* __restrict__ cnt8,
    uint* __restrict__ sums0, uint* __restrict__ cnt0)
{
  __shared__ float2 red[8][32];
  __shared__ uint redc[256];
  int b = blockIdx.x, t = threadIdx.x, c2 = t & 31, g = t >> 5;
  float sx = 0.f, sy = 0.f;
  for (int cell = g; cell < 4096; cell += 8) {
    uint u = sums8[(size_t)(b * 4096 + cell) * 32 + c2];
    sx += bflo(u); sy += bfhi(u);
  }
  red[g][c2] = make_float2(sx, sy);
  uint cn = 0;
  for (int i = t; i < 4096; i += 256) cn += cnt8[b * 4096 + i];
  redc[t] = cn;
  __syncthreads();
  if (g == 0) {
    float ax = 0.f, ay = 0.f;
    #pragma unroll
    for (int i = 0; i < 8; ++i) { ax += red[i][c2].x; ay += red[i][c2].y; }
    sums0[b * 32 + c2] = pack_bf16x2(ax, ay);
  }
  if (t == 0) {
    uint s = 0;
    for (int i = 0; i < 256; ++i) s += redc[i];
    cnt0[b] = s;
  }
}

// ---- fused gather-GEMM: per wave 16 points, A gathered from bf16 sums,
//      B (W) frag-ready in LDS, per-level acc, epilogue scales by 1/cnt.
#define GPB 4
__global__ __launch_bounds__(256) void k_final(
    const int* __restrict__ coords, const int* __restrict__ batch,
    const uint* __restrict__ sums0, const uint* __restrict__ cnt0,
    const uint* __restrict__ sums2, const uint* __restrict__ cnt2,
    const uint* __restrict__ sums4, const uint* __restrict__ cnt4,
    const uint* __restrict__ sums8, const uint* __restrict__ cnt8,
    const uint4* __restrict__ Wf, const float* __restrict__ bias,
    float* __restrict__ out)
{
  __shared__ uint4 wf[3072];   // 48 KB, frag-ready: [(kt*6+nt)*64 + lane]
  int t = threadIdx.x;
  #pragma unroll
  for (int i = 0; i < 12; ++i) wf[i * 256 + t] = Wf[i * 256 + t];
  __syncthreads();
  int l = t & 63, w = t >> 6, pl = l & 15, q = l >> 4;
  for (int g = 0; g < GPB; ++g) {
    int pbase = (blockIdx.x * GPB + g) * 64 + w * 16;
    int p = pbase + pl;                 // this lane's A-row point
    int b = batch[p];
    int x = coords[3 * p], y = coords[3 * p + 1], z = coords[3 * p + 2];
    int s2 = ((b * 64 + (x >> 1)) * 64 + (y >> 1)) * 64 + (z >> 1);
    int s4 = ((b * 32 + (x >> 2)) * 32 + (y >> 2)) * 32 + (z >> 2);
    int s8 = ((b * 16 + (x >> 3)) * 16 + (y >> 3)) * 16 + (z >> 3);
    const uint4* r0 = (const uint4*)(sums0 + (size_t)b * 32);
    const uint4* r2 = (const uint4*)(sums2 + (size_t)s2 * 32);
    const uint4* r4 = (const uint4*)(sums4 + (size_t)s4 * 32);
    const uint4* r8 = (const uint4*)(sums8 + (size_t)s8 * 32);
    uint4 araw[8];                      // lane l: A[pl][kt*32 + q*8 .. +7]
    araw[0] = r0[q];     araw[1] = r0[4 + q];
    araw[2] = r2[q];     araw[3] = r2[4 + q];
    araw[4] = r4[q];     araw[5] = r4[4 + q];
    araw[6] = r8[q];     araw[7] = r8[4 + q];
    uint c0v = cnt0[b], c2v = cnt2[s2], c4v = cnt4[s4], c8v = cnt8[s8];
    float rcv[4];
    rcv[0] = 1.0f / (float)(c0v > 1u ? c0v : 1u);
    rcv[1] = 1.0f / (float)(c2v > 1u ? c2v : 1u);
    rcv[2] = 1.0f / (float)(c4v > 1u ? c4v : 1u);
    rcv[3] = 1.0f / (float)(c8v > 1u ? c8v : 1u);
    f4v acc[4][6];
    #pragma unroll
    for (int lv = 0; lv < 4; ++lv)
      #pragma unroll
      for (int nt = 0; nt < 6; ++nt) acc[lv][nt] = (f4v)0.0f;
    #pragma unroll
    for (int kt = 0; kt < 8; ++kt) {
      s8v af = __builtin_bit_cast(s8v, araw[kt]);
      #pragma unroll
      for (int nt = 0; nt < 6; ++nt) {
        s8v bf = __builtin_bit_cast(s8v, wf[(kt * 6 + nt) * 64 + l]);
        acc[kt >> 1][nt] =
            __builtin_amdgcn_mfma_f32_16x16x32_bf16(af, bf, acc[kt >> 1][nt], 0, 0, 0);
      }
    }
    // D layout: row m = q*4+r, col = pl. rc for row m lives in lane m.
    float rr[4][4];
    #pragma unroll
    for (int r = 0; r < 4; ++r) {
      int src = q * 4 + r;
      #pragma unroll
      for (int lv = 0; lv < 4; ++lv) rr[lv][r] = __shfl(rcv[lv], src, 64);
    }
    #pragma unroll
    for (int nt = 0; nt < 6; ++nt) {
      float bn = bias[nt * 16 + pl];
      #pragma unroll
      for (int r = 0; r < 4; ++r) {
        float v = bn + acc[0][nt][r] * rr[0][r] + acc[1][nt][r] * rr[1][r]
                     + acc[2][nt][r] * rr[2][r] + acc[3][nt][r] * rr[3][r];
        out[(size_t)(pbase + q * 4 + r) * 96 + nt * 16 + pl] = v;
      }
    }
  }
}

extern "C" void kernel_launch(void* const* d_in, const int* in_sizes, int n_in,
                              void* d_out, int out_size, void* d_ws, size_t ws_size,
                              hipStream_t stream)
{
  const float* feats  = (const float*)d_in[0];
  const int*   coords = (const int*)d_in[1];
  const int*   batch  = (const int*)d_in[2];
  const float* W      = (const float*)d_in[3];
  const float* bias   = (const float*)d_in[4];
  float* out = (float*)d_out;
  char* ws = (char*)d_ws;
  if (ws_size < WS_NEEDED) return;

  uint* sums2 = (uint*)(ws + OFF_SUMS2);
  uint* cnt2  = (uint*)(ws + OFF_CNT2);
  uint* sums4 = (uint*)(ws + OFF_SUMS4);
  uint* cnt4  = (uint*)(ws + OFF_CNT4);
  uint* sums8 = (uint*)(ws + OFF_SUMS8);
  uint* cnt8  = (uint*)(ws + OFF_CNT8);
  uint* sums0 = (uint*)(ws + OFF_SUMS0);
  uint* cnt0  = (uint*)(ws + OFF_CNT0);
  uint* Wf    = (uint*)(ws + OFF_WF);

  // zero only the atomic-accumulated regions (sums2 + cnt2, contiguous)
  hipMemsetAsync(ws, 0, OFF_SUMS4, stream);

  k_wf<<<48, 256, 0, stream>>>(W, Wf);
  k_scatter2<<<8192, 256, 0, stream>>>(feats, coords, batch, sums2, cnt2);
  k_down_bf<<<(N4SEG * 32) / 256, 256, 0, stream>>>(sums2, cnt2, sums4, cnt4, 5, N4SEG);
  k_down_bf<<<(N8SEG * 32) / 256, 256, 0, stream>>>(sums4, cnt4, sums8, cnt8, 4, N8SEG);
  k_global_bf<<<NB, 256, 0, stream>>>(sums8, cnt8, sums0, cnt0);
  k_final<<<N_PTS / (GPB * 64), 256, 0, stream>>>(
      coords, batch, sums0, cnt0, sums2, cnt2, sums4, cnt4, sums8, cnt8,
      (const uint4*)Wf, bias, out);
}

// Round 3
// 451.295 us; speedup vs baseline: 3.2004x; 1.3490x over previous
//
#include <hip/hip_runtime.h>
#include <stdint.h>

// ---------------------------------------------------------------------------
// SPP: out[n] = b + W @ [mean0(b) | mean2(s2) | mean4(s4) | mean8(s8)]
// v3: bf16 pk-atomic scatter -> bf16 pyramid (emitting pre-scaled means for
//     levels 0/4/8) -> fused MFMA gather-GEMM with single acc[6] (A-fragments
//     pre-scaled), 12 waves/CU target.
// ---------------------------------------------------------------------------

#define N_PTS   1048576
#define NB      4
#define N2SEG   (NB*64*64*64)   // 1,048,576
#define N4SEG   (NB*32*32*32)   // 131,072
#define N8SEG   (NB*16*16*16)   // 16,384

typedef unsigned int uint;

// workspace offsets (bytes)
#define OFF_SUMS2  ((size_t)0)            // N2SEG*64 bf16 = 134,217,728
#define OFF_CNT2   ((size_t)134217728)    // N2SEG u32     =   4,194,304
#define OFF_SUMS0F ((size_t)138412032)    // 256 f32 (pad 1024)
#define MEMSET_END ((size_t)138413056)
#define OFF_SUMS4  ((size_t)138413056)    // N4SEG*64 bf16 =  16,777,216
#define OFF_MEAN4  ((size_t)155190272)    // N4SEG*64 bf16 =  16,777,216
#define OFF_CNT4   ((size_t)171967488)    // N4SEG u32     =     524,288
#define OFF_SUMS8  ((size_t)172491776)    // N8SEG*64 bf16 =   2,097,152
#define OFF_MEAN8  ((size_t)174588928)    // N8SEG*64 bf16 =   2,097,152
#define OFF_CNT8   ((size_t)176686080)    // N8SEG u32     =      65,536
#define OFF_MEAN0  ((size_t)176751616)    // 4*32 u32 (pad 1024)
#define OFF_WF     ((size_t)176752640)    // 48 KB frag-ready W
#define WS_NEEDED  ((size_t)176801792)

typedef short s8v __attribute__((ext_vector_type(8)));   // 8 bf16 (4 VGPR)
typedef float f4v __attribute__((ext_vector_type(4)));   // MFMA C/D

__device__ __forceinline__ uint pack_bf16x2(float a, float b) {
  uint ua = __float_as_uint(a), ub = __float_as_uint(b);
  ua = (ua + 0x7fffu + ((ua >> 16) & 1u)) >> 16;   // RNE
  ub = (ub + 0x7fffu + ((ub >> 16) & 1u)) >> 16;
  return (ub << 16) | ua;
}
__device__ __forceinline__ float bflo(uint u) { return __uint_as_float(u << 16); }
__device__ __forceinline__ float bfhi(uint u) { return __uint_as_float(u & 0xffff0000u); }

__device__ __forceinline__ uint scale_pk(uint u, float rc) {
  return pack_bf16x2(bflo(u) * rc, bfhi(u) * rc);
}

// ---- frag-ready W: Wf[((kt*6+nt)*64+l)*4+d] = pack(W[n][k], W[n][k+1])
//      n = nt*16+(l&15), k = kt*32+(l>>4)*8+2d   (B[k][n] = W[n][k])
__global__ __launch_bounds__(256) void k_wf(const float* __restrict__ W,
                                            uint* __restrict__ Wf) {
  int idx = blockIdx.x * 256 + threadIdx.x;        // < 12288
  int d = idx & 3, l = (idx >> 2) & 63, ktnt = idx >> 8;
  int kt = ktnt / 6, nt = ktnt - kt * 6;
  int n = nt * 16 + (l & 15);
  int k = kt * 32 + (l >> 4) * 8 + d * 2;
  Wf[idx] = pack_bf16x2(W[n * 256 + k], W[n * 256 + k + 1]);
}

// ---- scatter: 2 points per wave, lane = (half, channel-pair), pk-bf16 atomics
__global__ __launch_bounds__(256) void k_scatter2(
    const float* __restrict__ feats, const int* __restrict__ coords,
    const int* __restrict__ batch, uint* __restrict__ sums2,
    uint* __restrict__ cnt2)
{
  int l = threadIdx.x & 63;
  int c2 = l & 31, half = l >> 5;
  int wid = (blockIdx.x * 256 + threadIdx.x) >> 6;
  int nw = (gridDim.x * 256) >> 6;
  for (int p0 = wid * 2; p0 < N_PTS; p0 += nw * 2) {
    int p = p0 + half;
    float2 f = ((const float2*)feats)[(size_t)p * 32 + c2];
    int b = batch[p];
    int x = coords[3 * p], y = coords[3 * p + 1], z = coords[3 * p + 2];
    int s2 = ((b * 64 + (x >> 1)) * 64 + (y >> 1)) * 64 + (z >> 1);
    uint pk = pack_bf16x2(f.x, f.y);
    uint64_t addr = (uint64_t)(uintptr_t)(sums2 + (size_t)s2 * 32 + c2);
    asm volatile("global_atomic_pk_add_bf16 %0, %1, off"
                 :: "v"(addr), "v"(pk) : "memory");
    if (c2 == 0) atomicAdd(&cnt2[s2], 1u);
  }
}

// ---- 8-child tree reduction; writes raw sums (next level), pre-scaled mean,
//      and cnt. thread = (sc, c2)
__global__ __launch_bounds__(256) void k_down_bf(
    const uint* __restrict__ sumsF, const uint* __restrict__ cntF,
    uint* __restrict__ sumsC, uint* __restrict__ meanC,
    uint* __restrict__ cntC, int lgC, int nC)
{
  int tid = blockIdx.x * 256 + threadIdx.x;
  int sc = tid >> 5, c2 = tid & 31;
  if (sc >= nC) return;
  int CG = 1 << lgC, FG = CG << 1;
  int b = sc >> (3 * lgC);
  int r = sc & ((1 << (3 * lgC)) - 1);
  int x = r >> (2 * lgC), y = (r >> lgC) & (CG - 1), z = r & (CG - 1);
  float sx = 0.f, sy = 0.f;
  uint cn = 0;
  #pragma unroll
  for (int dx = 0; dx < 2; ++dx)
    #pragma unroll
    for (int dy = 0; dy < 2; ++dy)
      #pragma unroll
      for (int dz = 0; dz < 2; ++dz) {
        int sf = ((b * FG + 2 * x + dx) * FG + (2 * y + dy)) * FG + (2 * z + dz);
        uint u = sumsF[(size_t)sf * 32 + c2];
        sx += bflo(u); sy += bfhi(u);
        cn += cntF[sf];                       // same addr across 32 lanes: L1 broadcast
      }
  sumsC[(size_t)sc * 32 + c2] = pack_bf16x2(sx, sy);
  float rc = 1.0f / (float)(cn > 1u ? cn : 1u);
  meanC[(size_t)sc * 32 + c2] = pack_bf16x2(sx * rc, sy * rc);
  if (c2 == 0) cntC[sc] = cn;
}

// ---- per-batch global partial reduce (32 blocks/batch), f32 atomics
__global__ __launch_bounds__(256) void k_gpart(
    const uint* __restrict__ sums8, float* __restrict__ sums0f)
{
  __shared__ float2 red[8][32];
  int b = blockIdx.x >> 5, chunk = blockIdx.x & 31;
  int t = threadIdx.x, c2 = t & 31, g = t >> 5;
  float sx = 0.f, sy = 0.f;
  for (int i = g; i < 128; i += 8) {
    uint u = sums8[(size_t)(b * 4096 + chunk * 128 + i) * 32 + c2];
    sx += bflo(u); sy += bfhi(u);
  }
  red[g][c2] = make_float2(sx, sy);
  __syncthreads();
  if (g == 0) {
    float ax = 0.f, ay = 0.f;
    #pragma unroll
    for (int i = 0; i < 8; ++i) { ax += red[i][c2].x; ay += red[i][c2].y; }
    unsafeAtomicAdd(&sums0f[b * 64 + 2 * c2], ax);
    unsafeAtomicAdd(&sums0f[b * 64 + 2 * c2 + 1], ay);
  }
}

// ---- finalize level 0: cnt0 from cnt8, mean0 = sums0f/cnt0 (bf16, pre-scaled)
__global__ __launch_bounds__(256) void k_fin0(
    const float* __restrict__ sums0f, const uint* __restrict__ cnt8,
    uint* __restrict__ mean0)
{
  __shared__ uint redc[256];
  __shared__ float rcs[NB];
  int t = threadIdx.x;
  uint cn = 0;
  for (int i = 0; i < 64; ++i) cn += cnt8[t * 64 + i];
  redc[t] = cn;
  __syncthreads();
  if (t < NB) {
    uint s = 0;
    for (int i = 0; i < 64; ++i) s += redc[t * 64 + i];
    rcs[t] = 1.0f / (float)(s > 1u ? s : 1u);
  }
  __syncthreads();
  if (t < 128) {
    int b = t >> 5, c2 = t & 31;
    float rc = rcs[b];
    mean0[b * 32 + c2] =
        pack_bf16x2(sums0f[b * 64 + 2 * c2] * rc, sums0f[b * 64 + 2 * c2 + 1] * rc);
  }
}

// ---- fused gather-GEMM: wave = 16 points; A gathered (level-2 scaled
//      in-register, others pre-scaled); B frag-ready in LDS; acc[6] only.
#define GPB 8
__global__ __launch_bounds__(256) void k_final(
    const int* __restrict__ coords, const int* __restrict__ batch,
    const uint* __restrict__ mean0,
    const uint* __restrict__ sums2, const uint* __restrict__ cnt2,
    const uint* __restrict__ mean4, const uint* __restrict__ mean8,
    const uint4* __restrict__ Wf, const float* __restrict__ bias,
    float* __restrict__ out)
{
  __shared__ uint4 wf[3072];   // 48 KB frag-ready W
  int t = threadIdx.x;
  #pragma unroll
  for (int i = 0; i < 12; ++i) wf[i * 256 + t] = Wf[i * 256 + t];
  __syncthreads();
  int l = t & 63, w = t >> 6, pl = l & 15, q = l >> 4;
  #pragma unroll 1
  for (int g = 0; g < GPB; ++g) {
    int pbase = (blockIdx.x * GPB + g) * 64 + w * 16;
    int p = pbase + pl;                 // this lane's A-row point
    int b = batch[p];
    int x = coords[3 * p], y = coords[3 * p + 1], z = coords[3 * p + 2];
    int s2 = ((b * 64 + (x >> 1)) * 64 + (y >> 1)) * 64 + (z >> 1);
    int s4 = ((b * 32 + (x >> 2)) * 32 + (y >> 2)) * 32 + (z >> 2);
    int s8 = ((b * 16 + (x >> 3)) * 16 + (y >> 3)) * 16 + (z >> 3);
    const uint4* r0 = (const uint4*)(mean0 + (size_t)b * 32);
    const uint4* r2 = (const uint4*)(sums2 + (size_t)s2 * 32);
    const uint4* r4 = (const uint4*)(mean4 + (size_t)s4 * 32);
    const uint4* r8 = (const uint4*)(mean8 + (size_t)s8 * 32);
    uint4 af[8];                        // lane l: A[pl][kt*32 + q*8 .. +7]
    af[0] = r0[q];     af[1] = r0[4 + q];
    af[2] = r2[q];     af[3] = r2[4 + q];
    af[4] = r4[q];     af[5] = r4[4 + q];
    af[6] = r8[q];     af[7] = r8[4 + q];
    uint cv = cnt2[s2];
    float rc = 1.0f / (float)(cv > 1u ? cv : 1u);
    af[2].x = scale_pk(af[2].x, rc); af[2].y = scale_pk(af[2].y, rc);
    af[2].z = scale_pk(af[2].z, rc); af[2].w = scale_pk(af[2].w, rc);
    af[3].x = scale_pk(af[3].x, rc); af[3].y = scale_pk(af[3].y, rc);
    af[3].z = scale_pk(af[3].z, rc); af[3].w = scale_pk(af[3].w, rc);
    f4v acc[6];
    #pragma unroll
    for (int nt = 0; nt < 6; ++nt) acc[nt] = (f4v)0.0f;
    #pragma unroll
    for (int kt = 0; kt < 8; ++kt) {
      s8v afr = __builtin_bit_cast(s8v, af[kt]);
      #pragma unroll
      for (int nt = 0; nt < 6; ++nt) {
        s8v bf = __builtin_bit_cast(s8v, wf[(kt * 6 + nt) * 64 + l]);
        acc[nt] = __builtin_amdgcn_mfma_f32_16x16x32_bf16(afr, bf, acc[nt], 0, 0, 0);
      }
    }
    // D layout: row m = q*4+r (point pbase+m), col = pl (channel nt*16+pl)
    #pragma unroll
    for (int nt = 0; nt < 6; ++nt) {
      float bn = bias[nt * 16 + pl];
      #pragma unroll
      for (int r = 0; r < 4; ++r)
        out[(size_t)(pbase + q * 4 + r) * 96 + nt * 16 + pl] = bn + acc[nt][r];
    }
  }
}

extern "C" void kernel_launch(void* const* d_in, const int* in_sizes, int n_in,
                              void* d_out, int out_size, void* d_ws, size_t ws_size,
                              hipStream_t stream)
{
  const float* feats  = (const float*)d_in[0];
  const int*   coords = (const int*)d_in[1];
  const int*   batch  = (const int*)d_in[2];
  const float* W      = (const float*)d_in[3];
  const float* bias   = (const float*)d_in[4];
  float* out = (float*)d_out;
  char* ws = (char*)d_ws;
  if (ws_size < WS_NEEDED) return;

  uint*  sums2  = (uint*)(ws + OFF_SUMS2);
  uint*  cnt2   = (uint*)(ws + OFF_CNT2);
  float* sums0f = (float*)(ws + OFF_SUMS0F);
  uint*  sums4  = (uint*)(ws + OFF_SUMS4);
  uint*  mean4  = (uint*)(ws + OFF_MEAN4);
  uint*  cnt4   = (uint*)(ws + OFF_CNT4);
  uint*  sums8  = (uint*)(ws + OFF_SUMS8);
  uint*  mean8  = (uint*)(ws + OFF_MEAN8);
  uint*  cnt8   = (uint*)(ws + OFF_CNT8);
  uint*  mean0  = (uint*)(ws + OFF_MEAN0);
  uint*  Wf     = (uint*)(ws + OFF_WF);

  // zero atomic-accumulated regions (sums2 + cnt2 + sums0f, contiguous)
  hipMemsetAsync(ws, 0, MEMSET_END, stream);

  k_wf<<<48, 256, 0, stream>>>(W, Wf);
  k_scatter2<<<8192, 256, 0, stream>>>(feats, coords, batch, sums2, cnt2);
  k_down_bf<<<(N4SEG * 32) / 256, 256, 0, stream>>>(sums2, cnt2, sums4, mean4, cnt4, 5, N4SEG);
  k_down_bf<<<(N8SEG * 32) / 256, 256, 0, stream>>>(sums4, cnt4, sums8, mean8, cnt8, 4, N8SEG);
  k_gpart<<<128, 256, 0, stream>>>(sums8, sums0f);
  k_fin0<<<1, 256, 0, stream>>>(sums0f, cnt8, mean0);
  k_final<<<N_PTS / (GPB * 64), 256, 0, stream>>>(
      coords, batch, mean0, sums2, cnt2, mean4, mean8,
      (const uint4*)Wf, bias, out);
}